// Round 1
// 199.672 us; speedup vs baseline: 1.0043x; 1.0043x over previous
//
#include <hip/hip_runtime.h>

// Bicubic 4x upscale, Keys a=-0.5, jax.image.resize semantics:
// sample s = (o+0.5)/4 - 0.5; OOB taps dropped + weights renormalized.
//
// v2: persistent blocks, 3 row-groups per block (grid = 1024 = exactly
// 4 blocks/CU in ONE generation), double-buffered LDS tile, register
// prefetch of group i+1's 8 input rows issued right after the barrier so
// HBM load latency hides under group i's compute+store burst. Exactly one
// __syncthreads() per group (double buffering: write(i+2) vs read(i) is
// ordered by barrier(i+1)). Goal: keep the per-CU store stream continuous
// instead of stalling it at every block generation on cold input loads.

#define Hin 256
#define Win 256
#define GPB 3            // row-groups per block; 3072 groups / 3 = 1024 blocks
#define LDSW (Win + 4)

#define WK00 -0.0439453125f
#define WK01  0.3896484375f
#define WK02  0.7275390625f
#define WK03 -0.0732421875f
#define WK10 -0.0068359375f
#define WK11  0.0908203125f
#define WK12  0.9638671875f
#define WK13 -0.0478515625f

__global__ __launch_bounds__(256, 4) void cubic_up4(const float* __restrict__ in,
                                                    float* __restrict__ out) {
    const int jx = threadIdx.x;          // input column 0..255

    // double-buffered guard-padded tile: 2 x 8 rows x (256+4) cols
    __shared__ float sv[2][8][LDSW];

    // zero guard columns ONCE for both buffers (staging never touches them)
    if (jx < 2) {
#pragma unroll
        for (int b = 0; b < 2; ++b)
#pragma unroll
            for (int r = 0; r < 8; ++r) sv[b][r][jx] = 0.f;
    }
    if (jx >= Win - 2) {
#pragma unroll
        for (int b = 0; b < 2; ++b)
#pragma unroll
            for (int r = 0; r < 8; ++r) sv[b][r][jx + 4] = 0.f;
    }

    const float WK[4][4] = {{WK00, WK01, WK02, WK03},
                            {WK10, WK11, WK12, WK13},
                            {WK13, WK12, WK11, WK10},
                            {WK03, WK02, WK01, WK00}};

    const int g0 = blockIdx.x * GPB;     // first group id (group = bc*64 + jy4)

    // ---- prologue: load group g0's 8 rows into registers ----
    float pre[8];
    {
        const int bc = g0 >> 6;
        const int jy0 = (g0 & 63) << 2;
        const float* __restrict__ inp = in + (size_t)bc * (Hin * Win);
#pragma unroll
        for (int r = 0; r < 8; ++r) {
            int ry = jy0 - 2 + r;
            ry = ry < 0 ? 0 : (ry > Hin - 1 ? Hin - 1 : ry);
            pre[r] = inp[ry * Win + jx];
        }
    }

#pragma unroll
    for (int i = 0; i < GPB; ++i) {
        const int g = g0 + i;
        const int jy4 = g & 63;
        const int jy0 = jy4 << 2;
        float* __restrict__ outp = out + (size_t)(g >> 6) * ((size_t)Hin * Win * 16);

        float(*sb)[LDSW] = sv[i & 1];    // i unrolled -> static buffer select

        // stage current group's rows from regs into LDS
#pragma unroll
        for (int r = 0; r < 8; ++r) sb[r][jx + 2] = pre[r];
        __syncthreads();                 // the ONE barrier per group

        // prefetch next group's rows; lands during this group's compute+stores
        if (i + 1 < GPB) {
            const int gn = g + 1;
            const int bcn = gn >> 6;
            const int jy0n = (gn & 63) << 2;
            const float* __restrict__ inpn = in + (size_t)bcn * (Hin * Win);
#pragma unroll
            for (int r = 0; r < 8; ++r) {
                int ry = jy0n - 2 + r;
                ry = ry < 0 ? 0 : (ry > Hin - 1 ? Hin - 1 : ry);
                pre[r] = inpn[ry * Win + jx];
            }
        }

        // ---- horizontal pass: 8 rows x 4 phases ----
        float h[8][4];
        const bool xedge = (jx < 2) | (jx >= Win - 2);
        if (!xedge) {
#pragma unroll
            for (int r = 0; r < 8; ++r) {
                const float* p = &sb[r][jx];
                const float a0 = p[0], a1 = p[1], a2 = p[2], a3 = p[3], a4 = p[4];
                h[r][0] = WK00 * a0 + WK01 * a1 + WK02 * a2 + WK03 * a3;
                h[r][1] = WK10 * a0 + WK11 * a1 + WK12 * a2 + WK13 * a3;
                h[r][2] = WK13 * a1 + WK12 * a2 + WK11 * a3 + WK10 * a4;
                h[r][3] = WK03 * a1 + WK02 * a2 + WK01 * a3 + WK00 * a4;
            }
        } else {
            // edge columns: drop OOB taps, renormalize
            float wx[4][4];
#pragma unroll
            for (int r = 0; r < 4; ++r) {
                const int o = r >> 1;
                float s = 0.f;
#pragma unroll
                for (int t = 0; t < 4; ++t) {
                    const int c = jx - 2 + o + t;
                    const float w = (c >= 0 && c < Win) ? WK[r][t] : 0.f;
                    wx[r][t] = w;
                    s += w;
                }
                const float inv = __builtin_amdgcn_rcpf(s);
#pragma unroll
                for (int t = 0; t < 4; ++t) wx[r][t] *= inv;
            }
#pragma unroll
            for (int r = 0; r < 8; ++r) {
                const float* p = &sb[r][jx];  // dropped taps hit zeroed guards
#pragma unroll
                for (int rx = 0; rx < 4; ++rx) {
                    const int o = rx >> 1;
                    h[r][rx] = wx[rx][0] * p[o] + wx[rx][1] * p[o + 1] +
                               wx[rx][2] * p[o + 2] + wx[rx][3] * p[o + 3];
                }
            }
        }

        // ---- vertical pass + stores: 4 input rows x 4 phases ----
        const bool yedge = (jy4 == 0) | (jy4 == 63);
        if (!yedge) {
#pragma unroll
            for (int ty = 0; ty < 4; ++ty) {
#pragma unroll
                for (int ry = 0; ry < 4; ++ry) {
                    const int o = ty + (ry >> 1);
                    float4 res;
                    float* rp = (float*)&res;
#pragma unroll
                    for (int rx = 0; rx < 4; ++rx) {
                        rp[rx] = WK[ry][0] * h[o][rx] + WK[ry][1] * h[o + 1][rx] +
                                 WK[ry][2] * h[o + 2][rx] + WK[ry][3] * h[o + 3][rx];
                    }
                    *(float4*)(outp + (size_t)((jy4 << 4) + (ty << 2) + ry) * (Win * 4) +
                               (jx << 2)) = res;
                }
            }
        } else {
#pragma unroll
            for (int ty = 0; ty < 4; ++ty) {
                const int jy = jy0 + ty;
                float wy[4][4];
#pragma unroll
                for (int r = 0; r < 4; ++r) {
                    const int o = r >> 1;
                    float s = 0.f;
#pragma unroll
                    for (int t = 0; t < 4; ++t) {
                        const int c = jy - 2 + o + t;
                        const float w = (c >= 0 && c < Hin) ? WK[r][t] : 0.f;
                        wy[r][t] = w;
                        s += w;
                    }
                    const float inv = __builtin_amdgcn_rcpf(s);
#pragma unroll
                    for (int t = 0; t < 4; ++t) wy[r][t] *= inv;
                }
#pragma unroll
                for (int ry = 0; ry < 4; ++ry) {
                    const int o = ty + (ry >> 1);
                    float4 res;
                    float* rp = (float*)&res;
#pragma unroll
                    for (int rx = 0; rx < 4; ++rx) {
                        rp[rx] = wy[ry][0] * h[o][rx] + wy[ry][1] * h[o + 1][rx] +
                                 wy[ry][2] * h[o + 2][rx] + wy[ry][3] * h[o + 3][rx];
                    }
                    *(float4*)(outp + (size_t)((jy4 << 4) + (ty << 2) + ry) * (Win * 4) +
                               (jx << 2)) = res;
                }
            }
        }
    }
}

extern "C" void kernel_launch(void* const* d_in, const int* in_sizes, int n_in,
                              void* d_out, int out_size, void* d_ws, size_t ws_size,
                              hipStream_t stream) {
    const float* x = (const float*)d_in[0];
    float* out = (float*)d_out;
    // 3072 row-groups / 3 per block = 1024 blocks = exactly 4 blocks/CU.
    cubic_up4<<<dim3(1024), dim3(256), 0, stream>>>(x, out);
}